// Round 1
// baseline (100.394 us; speedup 1.0000x reference)
//
#include <hip/hip_runtime.h>

#define NN 32
#define CC 256
#define HH 56
#define WW 56
#define HWSZ 3136            // 56*56
#define QPP 784              // float4 quads per spatial plane (3136/4)
#define NHW 100352           // 32*3136
#define TOT4 6422528         // 32*256*3136/4

// ---------------- K1: channel max + mean pool ----------------
// grid: 392 blocks, block: (64,4). Each block covers 64 float4-quads (256 hw
// positions); threadIdx.y splits the 256 channels into 4 groups of 64.
__global__ __launch_bounds__(256) void k_pool(const float* __restrict__ x,
                                              float* __restrict__ pool,
                                              float* __restrict__ stats) {
    if (blockIdx.x == 0 && threadIdx.x == 0 && threadIdx.y == 0) {
        stats[0] = 0.f;
        stats[1] = 0.f;
    }
    const int tx = threadIdx.x;              // 0..63 quad-in-tile
    const int ty = threadIdx.y;              // 0..3 channel group
    const int qid = blockIdx.x * 64 + tx;    // global quad over N*HW
    const int n = qid / QPP;
    const int hwq = qid - n * QPP;

    const float4* p = (const float4*)x + (size_t)(n * CC + ty * 64) * QPP + hwq;
    float4 v0 = p[0];
    float4 vmax = v0;
    float4 vsum = v0;
#pragma unroll 8
    for (int i = 1; i < 64; ++i) {
        float4 v = p[(size_t)i * QPP];
        vmax.x = fmaxf(vmax.x, v.x); vmax.y = fmaxf(vmax.y, v.y);
        vmax.z = fmaxf(vmax.z, v.z); vmax.w = fmaxf(vmax.w, v.w);
        vsum.x += v.x; vsum.y += v.y; vsum.z += v.z; vsum.w += v.w;
    }
    __shared__ float4 smax[4][64];
    __shared__ float4 ssum[4][64];
    smax[ty][tx] = vmax;
    ssum[ty][tx] = vsum;
    __syncthreads();
    if (ty == 0) {
        float4 m = smax[0][tx];
        float4 s = ssum[0][tx];
#pragma unroll
        for (int g = 1; g < 4; ++g) {
            float4 mg = smax[g][tx];
            float4 sg = ssum[g][tx];
            m.x = fmaxf(m.x, mg.x); m.y = fmaxf(m.y, mg.y);
            m.z = fmaxf(m.z, mg.z); m.w = fmaxf(m.w, mg.w);
            s.x += sg.x; s.y += sg.y; s.z += sg.z; s.w += sg.w;
        }
        float4* pm = (float4*)pool + (size_t)n * 2 * QPP + hwq;
        pm[0] = m;                       // channel 0: max
        float4 mean;
        const float inv = 1.f / 256.f;
        mean.x = s.x * inv; mean.y = s.y * inv;
        mean.z = s.z * inv; mean.w = s.w * inv;
        pm[QPP] = mean;                  // channel 1: mean
    }
}

// ---------------- K2: 5x5 conv (2->1 ch, SAME) + BN stat partials ----------
// grid: 392 blocks x 256 threads, one thread per output element.
__global__ __launch_bounds__(256) void k_conv(const float* __restrict__ pool,
                                              const float* __restrict__ cw,
                                              float* __restrict__ conv,
                                              float* __restrict__ stats) {
    __shared__ float w[50];
    const int tid = threadIdx.x;
    if (tid < 50) w[tid] = cw[tid];
    __syncthreads();

    const int gid = blockIdx.x * 256 + tid;   // 0..NHW-1
    const int n = gid / HWSZ;
    const int hw = gid - n * HWSZ;
    const int h = hw / WW;
    const int wc = hw - h * WW;

    const float* pb = pool + (size_t)n * 2 * HWSZ;
    float acc = 0.f;
#pragma unroll
    for (int ci = 0; ci < 2; ++ci) {
#pragma unroll
        for (int kh = 0; kh < 5; ++kh) {
            const int hh = h + kh - 2;
            if (hh < 0 || hh >= HH) continue;
#pragma unroll
            for (int kw = 0; kw < 5; ++kw) {
                const int wwc = wc + kw - 2;
                if (wwc < 0 || wwc >= WW) continue;
                acc += pb[ci * HWSZ + hh * WW + wwc] * w[ci * 25 + kh * 5 + kw];
            }
        }
    }
    conv[gid] = acc;

    // wave64 reduce of sum / sumsq, then one atomic per wave
    float s = acc;
    float s2 = acc * acc;
#pragma unroll
    for (int i = 1; i < 64; i <<= 1) {
        s += __shfl_xor(s, i);
        s2 += __shfl_xor(s2, i);
    }
    if ((tid & 63) == 0) {
        atomicAdd(&stats[0], s);
        atomicAdd(&stats[1], s2);
    }
}

// ---------------- K3: finalize BN + double-sigmoid gate --------------------
__global__ __launch_bounds__(256) void k_gate(const float* __restrict__ conv,
                                              const float* __restrict__ stats,
                                              const float* __restrict__ gamma,
                                              const float* __restrict__ beta,
                                              float* __restrict__ gate) {
    const int gid = blockIdx.x * 256 + threadIdx.x;
    const float invM = 1.f / (float)NHW;
    const float mean = stats[0] * invM;
    const float var = stats[1] * invM - mean * mean;
    const float scale = rsqrtf(var + 1e-5f) * gamma[0];
    const float shift = beta[0] - mean * scale;
    const float v = conv[gid] * scale + shift;
    const float s1 = 1.f / (1.f + __expf(-v));
    gate[gid] = 1.f / (1.f + __expf(-s1));
}

// ---------------- K4: out = x * gate (broadcast over C) --------------------
__global__ __launch_bounds__(256) void k_apply(const float* __restrict__ x,
                                               const float* __restrict__ gate,
                                               float* __restrict__ out) {
    const float4* x4 = (const float4*)x;
    const float4* g4 = (const float4*)gate;
    float4* o4 = (float4*)out;
    for (int q = blockIdx.x * blockDim.x + threadIdx.x; q < TOT4;
         q += gridDim.x * blockDim.x) {
        const int plane = q / QPP;           // (n,c) plane index
        const int hwq = q - plane * QPP;
        const int n = plane >> 8;            // /CC
        float4 xv = x4[q];
        float4 gv = g4[n * QPP + hwq];
        float4 r;
        r.x = xv.x * gv.x; r.y = xv.y * gv.y;
        r.z = xv.z * gv.z; r.w = xv.w * gv.w;
        o4[q] = r;
    }
}

extern "C" void kernel_launch(void* const* d_in, const int* in_sizes, int n_in,
                              void* d_out, int out_size, void* d_ws, size_t ws_size,
                              hipStream_t stream) {
    const float* x = (const float*)d_in[0];
    const float* cw = (const float*)d_in[1];
    const float* gamma = (const float*)d_in[2];
    const float* beta = (const float*)d_in[3];
    float* out = (float*)d_out;

    float* ws = (float*)d_ws;
    float* pool = ws;                 // 2*NHW floats
    float* conv = ws + 2 * NHW;       // NHW floats
    float* gate = ws + 3 * NHW;       // NHW floats
    float* stats = ws + 4 * NHW;      // 2 floats

    k_pool<<<392, dim3(64, 4), 0, stream>>>(x, pool, stats);
    k_conv<<<392, 256, 0, stream>>>(pool, cw, conv, stats);
    k_gate<<<392, 256, 0, stream>>>(conv, stats, gamma, beta, gate);
    k_apply<<<2048, 256, 0, stream>>>(x, gate, out);
}

// Round 2
// 99.376 us; speedup vs baseline: 1.0102x; 1.0102x over previous
//
#include <hip/hip_runtime.h>

#define NN 32
#define CC 256
#define HH 56
#define WW 56
#define HWSZ 3136            // 56*56
#define QPP 784              // float4 quads per spatial plane (3136/4)
#define NHW 100352           // 32*3136
#define TOT4 6422528         // 32*256*3136/4

// ---------------- K1: channel max + mean pool ----------------
// grid: 392 blocks, block: (64,8). Each block covers 64 float4-quads (256 hw
// positions); threadIdx.y splits the 256 channels into 8 groups of 32.
// 512 thr/block -> 3136 waves -> ~12 waves/CU for latency hiding.
__global__ __launch_bounds__(512) void k_pool(const float* __restrict__ x,
                                              float* __restrict__ pool,
                                              float* __restrict__ stats) {
    if (blockIdx.x == 0 && threadIdx.x == 0 && threadIdx.y == 0) {
        stats[0] = 0.f;
        stats[1] = 0.f;
    }
    const int tx = threadIdx.x;              // 0..63 quad-in-tile
    const int ty = threadIdx.y;              // 0..7 channel group (32 ch each)
    const int qid = blockIdx.x * 64 + tx;    // global quad over N*HW
    const int n = qid / QPP;
    const int hwq = qid - n * QPP;

    const float4* p = (const float4*)x + (size_t)(n * CC + ty * 32) * QPP + hwq;
    float4 v0 = p[0];
    float4 vmax = v0;
    float4 vsum = v0;
#pragma unroll 8
    for (int i = 1; i < 32; ++i) {
        float4 v = p[(size_t)i * QPP];
        vmax.x = fmaxf(vmax.x, v.x); vmax.y = fmaxf(vmax.y, v.y);
        vmax.z = fmaxf(vmax.z, v.z); vmax.w = fmaxf(vmax.w, v.w);
        vsum.x += v.x; vsum.y += v.y; vsum.z += v.z; vsum.w += v.w;
    }
    __shared__ float4 smax[8][64];
    __shared__ float4 ssum[8][64];
    smax[ty][tx] = vmax;
    ssum[ty][tx] = vsum;
    __syncthreads();
    if (ty == 0) {
        float4 m = smax[0][tx];
        float4 s = ssum[0][tx];
#pragma unroll
        for (int g = 1; g < 8; ++g) {
            float4 mg = smax[g][tx];
            float4 sg = ssum[g][tx];
            m.x = fmaxf(m.x, mg.x); m.y = fmaxf(m.y, mg.y);
            m.z = fmaxf(m.z, mg.z); m.w = fmaxf(m.w, mg.w);
            s.x += sg.x; s.y += sg.y; s.z += sg.z; s.w += sg.w;
        }
        float4* pm = (float4*)pool + (size_t)n * 2 * QPP + hwq;
        pm[0] = m;                       // channel 0: max
        float4 mean;
        const float inv = 1.f / 256.f;
        mean.x = s.x * inv; mean.y = s.y * inv;
        mean.z = s.z * inv; mean.w = s.w * inv;
        pm[QPP] = mean;                  // channel 1: mean
    }
}

// ---------------- K2: 5x5 conv (2->1 ch, SAME) + BN stat partials ----------
// grid: 392 blocks x 256 threads, one thread per output element.
__global__ __launch_bounds__(256) void k_conv(const float* __restrict__ pool,
                                              const float* __restrict__ cw,
                                              float* __restrict__ conv,
                                              float* __restrict__ stats) {
    __shared__ float w[50];
    const int tid = threadIdx.x;
    if (tid < 50) w[tid] = cw[tid];
    __syncthreads();

    const int gid = blockIdx.x * 256 + tid;   // 0..NHW-1
    const int n = gid / HWSZ;
    const int hw = gid - n * HWSZ;
    const int h = hw / WW;
    const int wc = hw - h * WW;

    const float* pb = pool + (size_t)n * 2 * HWSZ;
    float acc = 0.f;
#pragma unroll
    for (int ci = 0; ci < 2; ++ci) {
#pragma unroll
        for (int kh = 0; kh < 5; ++kh) {
            const int hh = h + kh - 2;
            if (hh < 0 || hh >= HH) continue;
#pragma unroll
            for (int kw = 0; kw < 5; ++kw) {
                const int wwc = wc + kw - 2;
                if (wwc < 0 || wwc >= WW) continue;
                acc += pb[ci * HWSZ + hh * WW + wwc] * w[ci * 25 + kh * 5 + kw];
            }
        }
    }
    conv[gid] = acc;

    // wave64 reduce of sum / sumsq, then one atomic per wave
    float s = acc;
    float s2 = acc * acc;
#pragma unroll
    for (int i = 1; i < 64; i <<= 1) {
        s += __shfl_xor(s, i);
        s2 += __shfl_xor(s2, i);
    }
    if ((tid & 63) == 0) {
        atomicAdd(&stats[0], s);
        atomicAdd(&stats[1], s2);
    }
}

// ---------------- K3: fused BN + double-sigmoid gate + apply ---------------
// out = x * sigmoid(sigmoid(bn(conv)))  -- gate recomputed per quad; conv
// array (400 KB) is L2/L3-resident and VALU is idle in this memory-bound
// kernel, so recomputation is free and kills the separate gate kernel.
__global__ __launch_bounds__(256) void k_apply(const float* __restrict__ x,
                                               const float* __restrict__ conv,
                                               const float* __restrict__ stats,
                                               const float* __restrict__ gamma,
                                               const float* __restrict__ beta,
                                               float* __restrict__ out) {
    const float invM = 1.f / (float)NHW;
    const float mean = stats[0] * invM;
    const float var = stats[1] * invM - mean * mean;
    const float scale = rsqrtf(var + 1e-5f) * gamma[0];
    const float shift = beta[0] - mean * scale;

    const float4* x4 = (const float4*)x;
    const float4* c4 = (const float4*)conv;
    float4* o4 = (float4*)out;
    for (int q = blockIdx.x * blockDim.x + threadIdx.x; q < TOT4;
         q += gridDim.x * blockDim.x) {
        const int plane = q / QPP;           // (n,c) plane index
        const int hwq = q - plane * QPP;
        const int n = plane >> 8;            // /CC
        float4 cv = c4[n * QPP + hwq];
        float4 xv = x4[q];
        float4 r;
        {
            float v = cv.x * scale + shift;
            float s1 = 1.f / (1.f + __expf(-v));
            r.x = xv.x * (1.f / (1.f + __expf(-s1)));
        }
        {
            float v = cv.y * scale + shift;
            float s1 = 1.f / (1.f + __expf(-v));
            r.y = xv.y * (1.f / (1.f + __expf(-s1)));
        }
        {
            float v = cv.z * scale + shift;
            float s1 = 1.f / (1.f + __expf(-v));
            r.z = xv.z * (1.f / (1.f + __expf(-s1)));
        }
        {
            float v = cv.w * scale + shift;
            float s1 = 1.f / (1.f + __expf(-v));
            r.w = xv.w * (1.f / (1.f + __expf(-s1)));
        }
        o4[q] = r;
    }
}

extern "C" void kernel_launch(void* const* d_in, const int* in_sizes, int n_in,
                              void* d_out, int out_size, void* d_ws, size_t ws_size,
                              hipStream_t stream) {
    const float* x = (const float*)d_in[0];
    const float* cw = (const float*)d_in[1];
    const float* gamma = (const float*)d_in[2];
    const float* beta = (const float*)d_in[3];
    float* out = (float*)d_out;

    float* ws = (float*)d_ws;
    float* pool = ws;                 // 2*NHW floats
    float* conv = ws + 2 * NHW;       // NHW floats
    float* stats = ws + 3 * NHW;      // 2 floats

    k_pool<<<392, dim3(64, 8), 0, stream>>>(x, pool, stats);
    k_conv<<<392, 256, 0, stream>>>(pool, cw, conv, stats);
    k_apply<<<4096, 256, 0, stream>>>(x, conv, stats, gamma, beta, out);
}